// Round 4
// baseline (30646.545 us; speedup 1.0000x reference)
//
#include <hip/hip_runtime.h>
#include <cstdint>
#include <cstddef>

// ON-LSTM 3-layer RNN LM forward, fp32 baseline.
// T=128, B=64, V=10000, NINP=1024, NHID=2048
// layers: 0: 1024->2048, 1: 2048->2048, 2: 2048->1024

#define T_STEPS 128
#define BATCH   64
#define VOCAB   10000
#define KSPLIT  8

union F4 { float4 v; float f[4]; };

__device__ __forceinline__ float sigmoidf_(float x) { return 1.f / (1.f + expf(-x)); }

// ---------------- embedding gather: one block per row (t*64+b), 256 thr ----------------
__global__ void gather_emb(const int* __restrict__ tokens, const float* __restrict__ encW,
                           float* __restrict__ out, int row0) {
  int row = blockIdx.x;
  int tok = tokens[row0 + row];
  const float4* src = reinterpret_cast<const float4*>(encW + (size_t)tok * 1024);
  float4* dst = reinterpret_cast<float4*>(out + (size_t)row * 1024);
  dst[threadIdx.x] = src[threadIdx.x];
}

// ---------------- batched fp32 GEMM: C[M,N] = A[M,K] @ B[K,N] + bias ----------------
// 128x128 tile, BK=16, 256 threads, 8x8 per thread. K%16==0. M,N guarded.
__global__ __launch_bounds__(256) void gemm_bias_f32(
    const float* __restrict__ A, const float* __restrict__ B,
    const float* __restrict__ bias, float* __restrict__ C,
    int M, int K, int N) {
  __shared__ alignas(16) float As[16][128 + 4];
  __shared__ alignas(16) float Bs[16][128];
  const int tid = threadIdx.x;
  const int tm = tid >> 4, tn = tid & 15;
  const int bm = blockIdx.y * 128;
  const int bn = blockIdx.x * 128;
  const bool nfull = (bn + 128) <= N;
  const bool mfull = (bm + 128) <= M;

  float acc[8][8];
#pragma unroll
  for (int i = 0; i < 8; i++)
#pragma unroll
    for (int j = 0; j < 8; j++) acc[i][j] = 0.f;

  for (int k0 = 0; k0 < K; k0 += 16) {
    // A tile 128x16 -> As transposed [k][m]
#pragma unroll
    for (int j = 0; j < 2; j++) {
      int slot = tid + j * 256;
      int r = slot >> 2;           // 0..127
      int cv = (slot & 3) << 2;    // 0,4,8,12
      float4 v;
      if (mfull || bm + r < M) {
        v = *reinterpret_cast<const float4*>(A + (size_t)(bm + r) * K + k0 + cv);
      } else {
        v.x = v.y = v.z = v.w = 0.f;
      }
      As[cv + 0][r] = v.x; As[cv + 1][r] = v.y; As[cv + 2][r] = v.z; As[cv + 3][r] = v.w;
    }
    // B tile 16x128 direct
#pragma unroll
    for (int j = 0; j < 2; j++) {
      int slot = tid + j * 256;
      int r = slot >> 5;           // 0..15
      int cv = (slot & 31) << 2;   // 0..124
      int col = bn + cv;
      float4 v;
      if (nfull || col + 3 < N) {
        v = *reinterpret_cast<const float4*>(B + (size_t)(k0 + r) * N + col);
      } else {
        v.x = (col + 0 < N) ? B[(size_t)(k0 + r) * N + col + 0] : 0.f;
        v.y = (col + 1 < N) ? B[(size_t)(k0 + r) * N + col + 1] : 0.f;
        v.z = (col + 2 < N) ? B[(size_t)(k0 + r) * N + col + 2] : 0.f;
        v.w = (col + 3 < N) ? B[(size_t)(k0 + r) * N + col + 3] : 0.f;
      }
      *reinterpret_cast<float4*>(&Bs[r][cv]) = v;
    }
    __syncthreads();
#pragma unroll
    for (int kk = 0; kk < 16; kk++) {
      F4 a0, a1, b0, b1;
      a0.v = *reinterpret_cast<const float4*>(&As[kk][tm * 8]);
      a1.v = *reinterpret_cast<const float4*>(&As[kk][tm * 8 + 4]);
      b0.v = *reinterpret_cast<const float4*>(&Bs[kk][tn * 8]);
      b1.v = *reinterpret_cast<const float4*>(&Bs[kk][tn * 8 + 4]);
      float a[8] = {a0.f[0], a0.f[1], a0.f[2], a0.f[3], a1.f[0], a1.f[1], a1.f[2], a1.f[3]};
      float b[8] = {b0.f[0], b0.f[1], b0.f[2], b0.f[3], b1.f[0], b1.f[1], b1.f[2], b1.f[3]};
#pragma unroll
      for (int i = 0; i < 8; i++)
#pragma unroll
        for (int j = 0; j < 8; j++) acc[i][j] += a[i] * b[j];
    }
    __syncthreads();
  }

  float bvals[8];
#pragma unroll
  for (int j = 0; j < 8; j++) {
    int col = bn + tn * 8 + j;
    bvals[j] = (col < N) ? bias[col] : 0.f;
  }
#pragma unroll
  for (int i = 0; i < 8; i++) {
    int row = bm + tm * 8 + i;
    if (row >= M) break;
    float* crow = C + (size_t)row * N;
    if (nfull) {
      F4 o0, o1;
#pragma unroll
      for (int j = 0; j < 4; j++) { o0.f[j] = acc[i][j] + bvals[j]; o1.f[j] = acc[i][j + 4] + bvals[j + 4]; }
      *reinterpret_cast<float4*>(crow + bn + tn * 8) = o0.v;
      *reinterpret_cast<float4*>(crow + bn + tn * 8 + 4) = o1.v;
    } else {
#pragma unroll
      for (int j = 0; j < 8; j++) {
        int col = bn + tn * 8 + j;
        if (col < N) crow[col] = acc[i][j] + bvals[j];
      }
    }
  }
}

// ---------------- per-step recurrent GEMM: partials[ks][64][N] = h[64,K_slice] @ W ----------------
// 64x128 tile, split-K over blockIdx.y, 256 threads, 4x8 per thread. N%128==0, kslice%16==0.
__global__ __launch_bounds__(256) void step_gemm(
    const float* __restrict__ hvec, const float* __restrict__ W,
    float* __restrict__ part, int K, int N, int kslice) {
  __shared__ alignas(16) float As[16][64 + 4];
  __shared__ alignas(16) float Bs[16][128];
  const int tid = threadIdx.x;
  const int tm = tid >> 4, tn = tid & 15;
  const int bn = blockIdx.x * 128;
  const int k0 = blockIdx.y * kslice;

  float acc[4][8];
#pragma unroll
  for (int i = 0; i < 4; i++)
#pragma unroll
    for (int j = 0; j < 8; j++) acc[i][j] = 0.f;

  for (int kb = k0; kb < k0 + kslice; kb += 16) {
    {
      int r = tid >> 2, cv = (tid & 3) << 2;
      float4 v = *reinterpret_cast<const float4*>(hvec + (size_t)r * K + kb + cv);
      As[cv + 0][r] = v.x; As[cv + 1][r] = v.y; As[cv + 2][r] = v.z; As[cv + 3][r] = v.w;
    }
#pragma unroll
    for (int j = 0; j < 2; j++) {
      int slot = tid + j * 256;
      int r = slot >> 5, cv = (slot & 31) << 2;
      *reinterpret_cast<float4*>(&Bs[r][cv]) =
          *reinterpret_cast<const float4*>(W + (size_t)(kb + r) * N + bn + cv);
    }
    __syncthreads();
#pragma unroll
    for (int kk = 0; kk < 16; kk++) {
      F4 av, b0, b1;
      av.v = *reinterpret_cast<const float4*>(&As[kk][tm * 4]);
      b0.v = *reinterpret_cast<const float4*>(&Bs[kk][tn * 8]);
      b1.v = *reinterpret_cast<const float4*>(&Bs[kk][tn * 8 + 4]);
#pragma unroll
      for (int i = 0; i < 4; i++) {
#pragma unroll
        for (int j = 0; j < 4; j++) {
          acc[i][j]     += av.f[i] * b0.f[j];
          acc[i][j + 4] += av.f[i] * b1.f[j];
        }
      }
    }
    __syncthreads();
  }
  float* out = part + (size_t)blockIdx.y * 64 * N;
#pragma unroll
  for (int i = 0; i < 4; i++) {
    int row = tm * 4 + i;
    F4 o0, o1;
#pragma unroll
    for (int j = 0; j < 4; j++) { o0.f[j] = acc[i][j]; o1.f[j] = acc[i][j + 4]; }
    *reinterpret_cast<float4*>(out + (size_t)row * N + bn + tn * 8) = o0.v;
    *reinterpret_cast<float4*>(out + (size_t)row * N + bn + tn * 8 + 4) = o1.v;
  }
}

// ---------------- fused ON-LSTM cell: one block per batch row ----------------
// gates = X + sum(partials); softmax+cumsum over fm/im; elementwise cell update.
template <int H>
__global__ __launch_bounds__(256) void onlstm_cell(
    const float* __restrict__ Xrow,    // [64, 6H] at this timestep
    const float* __restrict__ part,    // [KSPLIT][64][6H]
    float* __restrict__ c_state,       // [64, H]
    float* __restrict__ h_state,       // [64, H]
    float* __restrict__ h_out) {       // [64, H]
  constexpr int NE = H / 256;
  constexpr int NG = NE / 4;
  constexpr int W6 = 6 * H;
  const int b = blockIdx.x;
  const int tid = threadIdx.x;
  const int lane = tid & 63, wid = tid >> 6;
  const int j0 = tid * NE;
  __shared__ float sred[8];

  const float* xr = Xrow + (size_t)b * W6;
  const float* pr = part + (size_t)b * W6;
  const size_t pstride = (size_t)64 * W6;

  auto loadg = [&](int c, int g) -> float4 {
    size_t off = (size_t)c * H + j0 + g * 4;
    F4 a; a.v = *reinterpret_cast<const float4*>(xr + off);
#pragma unroll
    for (int ks = 0; ks < KSPLIT; ks++) {
      F4 p; p.v = *reinterpret_cast<const float4*>(pr + (size_t)ks * pstride + off);
      a.f[0] += p.f[0]; a.f[1] += p.f[1]; a.f[2] += p.f[2]; a.f[3] += p.f[3];
    }
    return a.v;
  };

  float fm[NE], im[NE];
#pragma unroll
  for (int g = 0; g < NG; g++) {
    F4 vf, vi;
    vf.v = loadg(0, g);
    vi.v = loadg(1, g);
#pragma unroll
    for (int e = 0; e < 4; e++) { fm[g * 4 + e] = vf.f[e]; im[g * 4 + e] = vi.f[e]; }
  }
  float mf = -1e30f, mi = -1e30f;
#pragma unroll
  for (int e = 0; e < NE; e++) { mf = fmaxf(mf, fm[e]); mi = fmaxf(mi, im[e]); }
  // block max (4 waves)
#pragma unroll
  for (int off = 32; off > 0; off >>= 1) {
    mf = fmaxf(mf, __shfl_down(mf, off));
    mi = fmaxf(mi, __shfl_down(mi, off));
  }
  if (lane == 0) { sred[wid] = mf; sred[4 + wid] = mi; }
  __syncthreads();
  mf = fmaxf(fmaxf(sred[0], sred[1]), fmaxf(sred[2], sred[3]));
  mi = fmaxf(fmaxf(sred[4], sred[5]), fmaxf(sred[6], sred[7]));
  __syncthreads();

  float ef[NE], ei[NE];
  float sf = 0.f, si = 0.f;
#pragma unroll
  for (int e = 0; e < NE; e++) {
    ef[e] = expf(fm[e] - mf); sf += ef[e];
    ei[e] = expf(im[e] - mi); si += ei[e];
  }
  // block inclusive scan of per-thread sums -> exclusive prefix + totals
  float f = sf, ii = si;
#pragma unroll
  for (int off = 1; off < 64; off <<= 1) {
    float tf_ = __shfl_up(f, off);
    float ti_ = __shfl_up(ii, off);
    if (lane >= off) { f += tf_; ii += ti_; }
  }
  if (lane == 63) { sred[wid] = f; sred[4 + wid] = ii; }
  __syncthreads();
  float bf = 0.f, bi = 0.f, Tf = 0.f, Ti = 0.f;
#pragma unroll
  for (int w2 = 0; w2 < 4; w2++) {
    float wf = sred[w2], wi2 = sred[4 + w2];
    if (w2 < wid) { bf += wf; bi += wi2; }
    Tf += wf; Ti += wi2;
  }
  float pf = bf + f - sf;  // exclusive prefix for this thread
  float pi = bi + ii - si;
  float invTf = 1.f / Tf, invTi = 1.f / Ti;
  float cf[NE], ci[NE];
  float rf = pf, ri = pi;
#pragma unroll
  for (int e = 0; e < NE; e++) {
    rf += ef[e]; cf[e] = rf * invTf;          // cumsum(softmax(fm))
    ri += ei[e]; ci[e] = 1.f - ri * invTi;    // 1 - cumsum(softmax(im))
  }

#pragma unroll
  for (int g = 0; g < NG; g++) {
    F4 gi, gf2, gg, go, co, hn, cn;
    gi.v  = loadg(2, g);
    gf2.v = loadg(3, g);
    gg.v  = loadg(4, g);
    go.v  = loadg(5, g);
    co.v = *reinterpret_cast<const float4*>(c_state + (size_t)b * H + j0 + g * 4);
#pragma unroll
    for (int e2 = 0; e2 < 4; e2++) {
      int e = g * 4 + e2;
      float iv = sigmoidf_(gi.f[e2]);
      float fv = sigmoidf_(gf2.f[e2]);
      float gv = tanhf(gg.f[e2]);
      float ov = sigmoidf_(go.f[e2]);
      float olap = cf[e] * ci[e];
      float fh = fv * olap + (cf[e] - olap);
      float ih = iv * olap + (ci[e] - olap);
      float cne = fh * co.f[e2] + ih * gv;
      cn.f[e2] = cne;
      hn.f[e2] = ov * tanhf(cne);
    }
    *reinterpret_cast<float4*>(c_state + (size_t)b * H + j0 + g * 4) = cn.v;
    *reinterpret_cast<float4*>(h_state + (size_t)b * H + j0 + g * 4) = hn.v;
    *reinterpret_cast<float4*>(h_out  + (size_t)b * H + j0 + g * 4) = hn.v;
  }
}

extern "C" void kernel_launch(void* const* d_in, const int* in_sizes, int n_in,
                              void* d_out, int out_size, void* d_ws, size_t ws_size,
                              hipStream_t stream) {
  const int*   tokens = (const int*)d_in[0];
  const float* encW   = (const float*)d_in[1];
  const float* decW   = (const float*)d_in[2];
  const float* decb   = (const float*)d_in[3];
  const float* Wih[3] = {(const float*)d_in[4],  (const float*)d_in[9],  (const float*)d_in[14]};
  const float* Whh[3] = {(const float*)d_in[5],  (const float*)d_in[10], (const float*)d_in[15]};
  const float* bb[3]  = {(const float*)d_in[6],  (const float*)d_in[11], (const float*)d_in[16]};
  const float* h0[3]  = {(const float*)d_in[7],  (const float*)d_in[12], (const float*)d_in[17]};
  const float* c0[3]  = {(const float*)d_in[8],  (const float*)d_in[13], (const float*)d_in[18]};

  const int din[3]    = {1024, 2048, 2048};
  const int dout[3]   = {2048, 2048, 1024};
  const int ngates[3] = {12288, 12288, 6144};

  // workspace layout (floats), chunk size Tc adapted to ws_size
  const size_t wsf = ws_size / 4;
  int Tc = 1;
  {
    const int cands[8] = {128, 64, 32, 16, 8, 4, 2, 1};
    for (int k = 0; k < 8; k++) {
      size_t c = cands[k];
      size_t need = c * 64 * (12288 + 1024 + 2048 + 2048 + 1024)    // X, embc, H0c, H1c, H2c
                  + (size_t)KSPLIT * 64 * 12288                      // partials
                  + 2 * ((size_t)64 * 2048 * 2 + (size_t)64 * 1024); // h/c states
      if (need <= wsf) { Tc = (int)c; break; }
    }
  }

  float* w = (float*)d_ws;
  float* X    = w; w += (size_t)Tc * 64 * 12288;
  float* embc = w; w += (size_t)Tc * 64 * 1024;
  float* H0c  = w; w += (size_t)Tc * 64 * 2048;
  float* H1c  = w; w += (size_t)Tc * 64 * 2048;
  float* H2c  = w; w += (size_t)Tc * 64 * 1024;
  float* part = w; w += (size_t)KSPLIT * 64 * 12288;
  float* hs[3]; float* cs[3];
  hs[0] = w; w += 64 * 2048; cs[0] = w; w += 64 * 2048;
  hs[1] = w; w += 64 * 2048; cs[1] = w; w += 64 * 2048;
  hs[2] = w; w += 64 * 1024; cs[2] = w; w += 64 * 1024;

  for (int l = 0; l < 3; l++) {
    hipMemcpyAsync(hs[l], h0[l], (size_t)64 * dout[l] * sizeof(float), hipMemcpyDeviceToDevice, stream);
    hipMemcpyAsync(cs[l], c0[l], (size_t)64 * dout[l] * sizeof(float), hipMemcpyDeviceToDevice, stream);
  }

  float* out = (float*)d_out;
  const int nchunks = T_STEPS / Tc;
  for (int c = 0; c < nchunks; c++) {
    const int t0 = c * Tc;
    const int M = Tc * 64;
    const int Mg = (M + 127) / 128;

    gather_emb<<<M, 256, 0, stream>>>(tokens, encW, embc, t0 * 64);

    for (int l = 0; l < 3; l++) {
      const float* Ain  = (l == 0) ? embc : (l == 1) ? H0c : H1c;
      float*       Hout = (l == 0) ? H0c  : (l == 1) ? H1c : H2c;
      const int N = ngates[l];

      dim3 g(N / 128, Mg);
      gemm_bias_f32<<<g, 256, 0, stream>>>(Ain, Wih[l], bb[l], X, M, din[l], N);

      const int kslice = dout[l] / KSPLIT;
      dim3 sg(N / 128, KSPLIT);
      for (int tl = 0; tl < Tc; tl++) {
        step_gemm<<<sg, 256, 0, stream>>>(hs[l], Whh[l], part, dout[l], N, kslice);
        if (dout[l] == 2048) {
          onlstm_cell<2048><<<64, 256, 0, stream>>>(
              X + (size_t)tl * 64 * N, part, cs[l], hs[l], Hout + (size_t)tl * 64 * 2048);
        } else {
          onlstm_cell<1024><<<64, 256, 0, stream>>>(
              X + (size_t)tl * 64 * N, part, cs[l], hs[l], Hout + (size_t)tl * 64 * 1024);
        }
      }
    }

    dim3 dg((VOCAB + 127) / 128, Mg);
    gemm_bias_f32<<<dg, 256, 0, stream>>>(H2c, decW, decb, out + (size_t)t0 * 64 * VOCAB,
                                          M, 1024, VOCAB);
  }
}